// Round 16
// baseline (100.018 us; speedup 1.0000x reference)
//
#include <hip/hip_runtime.h>
#include <math.h>

#define N_NODES 10000
#define N_REL   500
#define H       128
#define L       128

#define TN    20     // n-tile: 500 * 20 = 10000 exactly
#define NBLK  500    // grid of k_main (2 blocks/CU)
#define PSTR  512    // psum row stride
#define REPS  3      // DIAGNOSTIC: main loop run 3x (output bit-identical)

__device__ __forceinline__ void gload16(const float* g, float* l) {
    __builtin_amdgcn_global_load_lds((const __attribute__((address_space(1))) void*)g,
                                     (__attribute__((address_space(3))) void*)l, 16, 0, 0);
}

// --- K1: per-block query rebuild + 128x20 exp(L1-dist) tile + psum ---------
// Structure identical to round 15 (best clean kernel, 27.0 us); the main
// loop is executed REPS times to surface k_main above the harness's 39 us
// poison-fills in rocprof with clean counters (no spill contamination).
__global__ __launch_bounds__(256)
__attribute__((amdgpu_waves_per_eu(2, 2)))
void k_main(const float* __restrict__ node,
            const float* __restrict__ rel,
            const int* __restrict__ eidx,
            const int* __restrict__ ridx,
            float* __restrict__ out,
            float* __restrict__ psum) {
    __shared__ union {
        float qs[L * H];            // 64 KB  (build + main-loop phase)
        float red[4][128][21];      // 43 KB  (merge phase, aliases qs)
    } u;
    __shared__ float es[TN * H];    // 10 KB
    __shared__ float invs[TN];

    const int tid  = threadIdx.x;
    const int w    = tid >> 6;          // wave id = h-segment in main loop
    const int lane = tid & 63;
    const int grp  = lane >> 2;         // 0..15
    const int nl   = lane & 3;          // 0..3
    const int nb   = blockIdx.x * TN;   // exact, no bounds checks
    const int hs   = w * 32;

    // ---- A1: issue es staging DMA (overlaps the query build below) ----
    {
        const int c0   = (lane & 31) << 2;
        const int roff = lane >> 5;
        #pragma unroll
        for (int k = 0; k < 10; ++k) {
            if ((k & 3) == w) {
                int r = k * 2;
                int row = r + roff;
                int g = (row & 7) << 2;
                gload16(node + (size_t)(nb + row) * H + (c0 ^ g), &es[r * H]);
            }
        }
    }

    // ---- A2: build all 128 query rows into qs (redundant per block) ----
    #pragma unroll
    for (int it = 0; it < 4; ++it) {
        int row = it * 32 + (tid >> 3);
        int seg = tid & 7;
        int ei = eidx[row], ri = ridx[row];
        const float4* pe = reinterpret_cast<const float4*>(node + (size_t)ei * H + seg * 16);
        const float4* pr = reinterpret_cast<const float4*>(rel  + (size_t)ri * H + seg * 16);
        float4 ev[4], rv[4];
        #pragma unroll
        for (int u2 = 0; u2 < 4; ++u2) { ev[u2] = pe[u2]; rv[u2] = pr[u2]; }
        float se = 0.f, sr = 0.f;
        #pragma unroll
        for (int u2 = 0; u2 < 4; ++u2) {
            se += ev[u2].x * ev[u2].x + ev[u2].y * ev[u2].y
                + ev[u2].z * ev[u2].z + ev[u2].w * ev[u2].w;
            sr += rv[u2].x * rv[u2].x + rv[u2].y * rv[u2].y
                + rv[u2].z * rv[u2].z + rv[u2].w * rv[u2].w;
        }
        se += __shfl_xor(se, 1, 64); se += __shfl_xor(se, 2, 64); se += __shfl_xor(se, 4, 64);
        sr += __shfl_xor(sr, 1, 64); sr += __shfl_xor(sr, 2, 64); sr += __shfl_xor(sr, 4, 64);
        float inve = 1.0f / fmaxf(sqrtf(se), 1e-12f);
        float invr = 1.0f / fmaxf(sqrtf(sr), 1e-12f);
        int g = (row & 7) << 2;
        float* dst = u.qs + row * H;
        #pragma unroll
        for (int u2 = 0; u2 < 4; ++u2) {
            float4 q;
            q.x = ev[u2].x * inve + rv[u2].x * invr;
            q.y = ev[u2].y * inve + rv[u2].y * invr;
            q.z = ev[u2].z * inve + rv[u2].z * invr;
            q.w = ev[u2].w * inve + rv[u2].w * invr;
            int c = (seg * 16 + u2 * 4) ^ g;        // 16B-aligned, swizzled
            *reinterpret_cast<float4*>(dst + c) = q;
        }
    }
    __syncthreads();   // drains es DMA (vmcnt) + qs LDS writes

    // ---- A3: inverse norms of the 20 es rows (swizzle-invariant) ----
    if (tid < 8 * TN) {
        int row = tid >> 3, seg = tid & 7;
        const float4* p = reinterpret_cast<const float4*>(es + row * H + seg * 16);
        float ss = 0.f;
        #pragma unroll
        for (int u2 = 0; u2 < 4; ++u2) {
            float4 v = p[u2];
            ss += v.x * v.x + v.y * v.y + v.z * v.z + v.w * v.w;
        }
        #pragma unroll
        for (int m = 1; m < 8; m <<= 1) ss += __shfl_xor(ss, m, 64);
        if (seg == 0) invs[row] = 1.0f / fmaxf(sqrtf(ss), 1e-12f);
    }
    __syncthreads();

    // ---- e-operand -> registers, scaled at load ----
    int gej[5];
    float sj[5];
    #pragma unroll
    for (int j = 0; j < 5; ++j) {
        gej[j] = ((nl + 4 * j) & 7) << 2;
        sj[j]  = invs[nl + 4 * j];
    }
    float4 ef[5][8];
    #pragma unroll
    for (int j = 0; j < 5; ++j)
        #pragma unroll
        for (int hc = 0; hc < 8; ++hc) {
            float4 t = *reinterpret_cast<const float4*>(
                &es[(nl + 4 * j) * H + ((hs + (hc << 2)) ^ gej[j])]);
            ef[j][hc].x = t.x * sj[j]; ef[j][hc].y = t.y * sj[j];
            ef[j][hc].z = t.z * sj[j]; ef[j][hc].w = t.w * sj[j];
        }

    // ---- B: main loop, run REPS times (diagnostic; bit-identical output) ----
    const int gq = (grp & 7) << 2;
    float acc[8][5];

    #pragma unroll 1
    for (int rep = 0; rep < REPS; ++rep) {
        asm volatile("" ::: "memory");   // force fresh qs ds_reads each rep
        #pragma unroll
        for (int i = 0; i < 8; ++i)
            #pragma unroll
            for (int j = 0; j < 5; ++j) acc[i][j] = 0.f;

        #pragma unroll
        for (int hc = 0; hc < 8; ++hc) {
            const int t = (hs + (hc << 2)) ^ gq;
            #pragma unroll
            for (int i = 0; i < 8; ++i) {
                float4 q4 = *reinterpret_cast<const float4*>(&u.qs[(grp + 16 * i) * H + t]);
                #pragma unroll
                for (int j = 0; j < 5; ++j)
                    acc[i][j] += fabsf(q4.x - ef[j][hc].x) + fabsf(q4.y - ef[j][hc].y)
                               + fabsf(q4.z - ef[j][hc].z) + fabsf(q4.w - ef[j][hc].w);
            }
        }

        #pragma unroll
        for (int i = 0; i < 8; ++i)
            #pragma unroll
            for (int j = 0; j < 5; ++j)
                asm volatile("" :: "v"(acc[i][j]));   // keep each rep live
    }

    // ---- merge 4 h-segment partials through LDS (aliases qs) ----
    __syncthreads();
    #pragma unroll
    for (int i = 0; i < 8; ++i)
        #pragma unroll
        for (int j = 0; j < 5; ++j)
            u.red[w][grp + 16 * i][nl + 4 * j] = acc[i][j];
    __syncthreads();

    // ---- epilogue: exp (no max: dist<=~34, f32-safe), store, psum ----
    {
        const int l  = tid >> 1;
        const int n0 = (tid & 1) * 10;
        float p[10];
        float rs = 0.f;
        #pragma unroll
        for (int k = 0; k < 10; ++k) {
            float d = u.red[0][l][n0 + k] + u.red[1][l][n0 + k]
                    + u.red[2][l][n0 + k] + u.red[3][l][n0 + k];
            p[k] = __expf(d);
            rs += p[k];
        }
        float* po = out + (size_t)l * N_NODES + nb + n0;
        #pragma unroll
        for (int k = 0; k < 5; ++k)
            *reinterpret_cast<float2*>(po + 2 * k) = make_float2(p[2 * k], p[2 * k + 1]);
        rs += __shfl_xor(rs, 1, 64);
        if ((tid & 1) == 0) psum[l * PSTR + blockIdx.x] = rs;
    }
}

// --- K2: finish softmax: per-row sum of 500 partials, scale ----------------
__global__ __launch_bounds__(256) void k_finish(float* __restrict__ out,
                                                const float* __restrict__ psum) {
    __shared__ float red[4];
    int l = blockIdx.y;
    int tid = threadIdx.x;
    const float* ps = psum + l * PSTR;
    float s = ps[tid] + (tid < NBLK - 256 ? ps[tid + 256] : 0.f);
    #pragma unroll
    for (int m = 1; m < 64; m <<= 1) s += __shfl_xor(s, m, 64);
    if ((tid & 63) == 0) red[tid >> 6] = s;
    __syncthreads();
    float inv = 1.0f / (red[0] + red[1] + red[2] + red[3]);

    int n4 = blockIdx.x * 256 + tid;           // float4 idx within row (<2500)
    if (n4 < 2500) {
        float4* o = reinterpret_cast<float4*>(out) + (size_t)l * 2500 + n4;
        float4 v = *o;
        v.x *= inv; v.y *= inv; v.z *= inv; v.w *= inv;
        *o = v;
    }
}

extern "C" void kernel_launch(void* const* d_in, const int* in_sizes, int n_in,
                              void* d_out, int out_size, void* d_ws, size_t ws_size,
                              hipStream_t stream) {
    const float* node = (const float*)d_in[0];
    const float* rel  = (const float*)d_in[1];
    const int*   eidx = (const int*)d_in[2];
    const int*   ridx = (const int*)d_in[3];
    float* out = (float*)d_out;

    float* psum = (float*)d_ws;               // 128*512 floats = 256 KB

    k_main<<<NBLK, 256, 0, stream>>>(node, rel, eidx, ridx, out, psum);

    dim3 gridC((2500 + 255) / 256, L);        // 10 x 128
    k_finish<<<gridC, 256, 0, stream>>>(out, psum);
}

// Round 17
// 63.981 us; speedup vs baseline: 1.5632x; 1.5632x over previous
//
#include <hip/hip_runtime.h>
#include <math.h>

#define N_NODES 10000
#define N_REL   500
#define H       128
#define L       128

#define TN    20     // n-tile: 500 * 20 = 10000 exactly
#define NBLK  500    // grid of k_main (2 blocks/CU)
#define PSTR  512    // psum row stride
#define REPS  3      // DIAGNOSTIC: main loop run 3x (output bit-identical)

__device__ __forceinline__ void gload16(const float* g, float* l) {
    __builtin_amdgcn_global_load_lds((const __attribute__((address_space(1))) void*)g,
                                     (__attribute__((address_space(3))) void*)l, 16, 0, 0);
}

// --- K1: r7 structure EXACTLY (best clean kernel, 27.0 us; loop live-set
// ~100 VGPR -> fits the observed 128 cap, no spill), with the main loop
// executed REPS times to surface clean counters above the 39 us poison-fills.
__global__ __launch_bounds__(256, 2) void k_main(const float* __restrict__ node,
                                                 const float* __restrict__ rel,
                                                 const int* __restrict__ eidx,
                                                 const int* __restrict__ ridx,
                                                 float* __restrict__ out,
                                                 float* __restrict__ psum) {
    __shared__ union {
        float qs[L * H];            // 64 KB  (build + main-loop phase)
        float red[4][128][21];      // 43 KB  (merge phase, aliases qs)
    } u;
    __shared__ float es[TN * H];    // 10 KB
    __shared__ float invs[TN];

    const int tid  = threadIdx.x;
    const int w    = tid >> 6;          // wave id = h-segment in main loop
    const int lane = tid & 63;
    const int grp  = lane >> 2;         // 0..15
    const int nl   = lane & 3;          // 0..3
    const int nb   = blockIdx.x * TN;   // exact, no bounds checks

    // ---- A1: issue es staging DMA (overlaps the query build below) ----
    {
        const int c0   = (lane & 31) << 2;
        const int roff = lane >> 5;
        #pragma unroll
        for (int k = 0; k < 10; ++k) {
            if ((k & 3) == w) {
                int r = k * 2;
                int row = r + roff;
                int g = (row & 7) << 2;
                gload16(node + (size_t)(nb + row) * H + (c0 ^ g), &es[r * H]);
            }
        }
    }

    // ---- A2: build all 128 query rows into qs (redundant per block) ----
    #pragma unroll
    for (int it = 0; it < 4; ++it) {
        int row = it * 32 + (tid >> 3);
        int seg = tid & 7;
        int ei = eidx[row], ri = ridx[row];
        const float4* pe = reinterpret_cast<const float4*>(node + (size_t)ei * H + seg * 16);
        const float4* pr = reinterpret_cast<const float4*>(rel  + (size_t)ri * H + seg * 16);
        float4 ev[4], rv[4];
        #pragma unroll
        for (int u2 = 0; u2 < 4; ++u2) { ev[u2] = pe[u2]; rv[u2] = pr[u2]; }
        float se = 0.f, sr = 0.f;
        #pragma unroll
        for (int u2 = 0; u2 < 4; ++u2) {
            se += ev[u2].x * ev[u2].x + ev[u2].y * ev[u2].y
                + ev[u2].z * ev[u2].z + ev[u2].w * ev[u2].w;
            sr += rv[u2].x * rv[u2].x + rv[u2].y * rv[u2].y
                + rv[u2].z * rv[u2].z + rv[u2].w * rv[u2].w;
        }
        se += __shfl_xor(se, 1, 64); se += __shfl_xor(se, 2, 64); se += __shfl_xor(se, 4, 64);
        sr += __shfl_xor(sr, 1, 64); sr += __shfl_xor(sr, 2, 64); sr += __shfl_xor(sr, 4, 64);
        float inve = 1.0f / fmaxf(sqrtf(se), 1e-12f);
        float invr = 1.0f / fmaxf(sqrtf(sr), 1e-12f);
        int g = (row & 7) << 2;
        float* dst = u.qs + row * H;
        #pragma unroll
        for (int u2 = 0; u2 < 4; ++u2) {
            float4 q;
            q.x = ev[u2].x * inve + rv[u2].x * invr;
            q.y = ev[u2].y * inve + rv[u2].y * invr;
            q.z = ev[u2].z * inve + rv[u2].z * invr;
            q.w = ev[u2].w * inve + rv[u2].w * invr;
            int c = (seg * 16 + u2 * 4) ^ g;        // 16B-aligned, swizzled
            *reinterpret_cast<float4*>(dst + c) = q;
        }
    }
    __syncthreads();   // drains es DMA (vmcnt) + qs LDS writes

    // ---- A3: inverse norms of the 20 es rows (swizzle-invariant) ----
    if (tid < 8 * TN) {
        int row = tid >> 3, seg = tid & 7;
        const float4* p = reinterpret_cast<const float4*>(es + row * H + seg * 16);
        float ss = 0.f;
        #pragma unroll
        for (int u2 = 0; u2 < 4; ++u2) {
            float4 v = p[u2];
            ss += v.x * v.x + v.y * v.y + v.z * v.z + v.w * v.w;
        }
        #pragma unroll
        for (int m = 1; m < 8; m <<= 1) ss += __shfl_xor(ss, m, 64);
        if (seg == 0) invs[row] = 1.0f / fmaxf(sqrtf(ss), 1e-12f);
    }
    __syncthreads();

    // ---- A4: scale es rows in place (640 float4) ----
    #pragma unroll
    for (int k = 0; k < 3; ++k) {
        int d4 = tid + (k << 8);
        if (d4 < TN * 32) {
            float s = invs[d4 >> 5];
            float4* p = reinterpret_cast<float4*>(es) + d4;
            float4 v = *p;
            v.x *= s; v.y *= s; v.z *= s; v.w *= s;
            *p = v;
        }
    }
    __syncthreads();

    // ---- B: main loop (r7 body), run REPS times -- diagnostic ----
    const int hs = w * 32;
    const int gq = (grp & 7) << 2;
    int gej[5];
    #pragma unroll
    for (int j = 0; j < 5; ++j) gej[j] = ((nl + 4 * j) & 7) << 2;

    float acc[8][5];

    #pragma unroll 1
    for (int rep = 0; rep < REPS; ++rep) {
        asm volatile("" ::: "memory");   // force fresh q AND e ds_reads each rep
        #pragma unroll
        for (int i = 0; i < 8; ++i)
            #pragma unroll
            for (int j = 0; j < 5; ++j) acc[i][j] = 0.f;

        #pragma unroll
        for (int hc = 0; hc < 8; ++hc) {
            const int h = hs + (hc << 2);
            float4 qf[8], ef[5];
            #pragma unroll
            for (int i = 0; i < 8; ++i)
                qf[i] = *reinterpret_cast<const float4*>(&u.qs[(grp + 16 * i) * H + (h ^ gq)]);
            #pragma unroll
            for (int j = 0; j < 5; ++j)
                ef[j] = *reinterpret_cast<const float4*>(&es[(nl + 4 * j) * H + (h ^ gej[j])]);
            #pragma unroll
            for (int i = 0; i < 8; ++i)
                #pragma unroll
                for (int j = 0; j < 5; ++j)
                    acc[i][j] += fabsf(qf[i].x - ef[j].x) + fabsf(qf[i].y - ef[j].y)
                               + fabsf(qf[i].z - ef[j].z) + fabsf(qf[i].w - ef[j].w);
        }

        #pragma unroll
        for (int i = 0; i < 8; ++i)
            #pragma unroll
            for (int j = 0; j < 5; ++j)
                asm volatile("" :: "v"(acc[i][j]));   // keep each rep live
    }

    // ---- merge 4 h-segment partials through LDS (aliases qs) ----
    __syncthreads();
    #pragma unroll
    for (int i = 0; i < 8; ++i)
        #pragma unroll
        for (int j = 0; j < 5; ++j)
            u.red[w][grp + 16 * i][nl + 4 * j] = acc[i][j];
    __syncthreads();

    // ---- epilogue: exp (no max: dist<=~34, f32-safe), store, psum ----
    {
        const int l  = tid >> 1;
        const int n0 = (tid & 1) * 10;
        float p[10];
        float rs = 0.f;
        #pragma unroll
        for (int k = 0; k < 10; ++k) {
            float d = u.red[0][l][n0 + k] + u.red[1][l][n0 + k]
                    + u.red[2][l][n0 + k] + u.red[3][l][n0 + k];
            p[k] = __expf(d);
            rs += p[k];
        }
        float* po = out + (size_t)l * N_NODES + nb + n0;
        #pragma unroll
        for (int k = 0; k < 5; ++k)
            *reinterpret_cast<float2*>(po + 2 * k) = make_float2(p[2 * k], p[2 * k + 1]);
        rs += __shfl_xor(rs, 1, 64);
        if ((tid & 1) == 0) psum[l * PSTR + blockIdx.x] = rs;
    }
}

// --- K2: finish softmax: per-row sum of 500 partials, scale ----------------
__global__ __launch_bounds__(256) void k_finish(float* __restrict__ out,
                                                const float* __restrict__ psum) {
    __shared__ float red[4];
    int l = blockIdx.y;
    int tid = threadIdx.x;
    const float* ps = psum + l * PSTR;
    float s = ps[tid] + (tid < NBLK - 256 ? ps[tid + 256] : 0.f);
    #pragma unroll
    for (int m = 1; m < 64; m <<= 1) s += __shfl_xor(s, m, 64);
    if ((tid & 63) == 0) red[tid >> 6] = s;
    __syncthreads();
    float inv = 1.0f / (red[0] + red[1] + red[2] + red[3]);

    int n4 = blockIdx.x * 256 + tid;           // float4 idx within row (<2500)
    if (n4 < 2500) {
        float4* o = reinterpret_cast<float4*>(out) + (size_t)l * 2500 + n4;
        float4 v = *o;
        v.x *= inv; v.y *= inv; v.z *= inv; v.w *= inv;
        *o = v;
    }
}

extern "C" void kernel_launch(void* const* d_in, const int* in_sizes, int n_in,
                              void* d_out, int out_size, void* d_ws, size_t ws_size,
                              hipStream_t stream) {
    const float* node = (const float*)d_in[0];
    const float* rel  = (const float*)d_in[1];
    const int*   eidx = (const int*)d_in[2];
    const int*   ridx = (const int*)d_in[3];
    float* out = (float*)d_out;

    float* psum = (float*)d_ws;               // 128*512 floats = 256 KB

    k_main<<<NBLK, 256, 0, stream>>>(node, rel, eidx, ridx, out, psum);

    dim3 gridC((2500 + 255) / 256, L);        // 10 x 128
    k_finish<<<gridC, 256, 0, stream>>>(out, psum);
}

// Round 18
// 31.837 us; speedup vs baseline: 3.1416x; 2.0097x over previous
//
#include <hip/hip_runtime.h>
#include <math.h>

#define N_NODES 10000
#define N_REL   500
#define H       128
#define L       128

#define TN    10     // n-tile: 1000 * 10 = 10000 exactly
#define NBLK  1000   // grid of k_main (~4 blocks/CU -> 4 waves/SIMD)
#define PSTR  1024   // psum row stride

__device__ __forceinline__ float waveReduceSum(float v) {
    #pragma unroll
    for (int m = 1; m < 64; m <<= 1) v += __shfl_xor(v, m, 64);
    return v;
}

__device__ __forceinline__ void gload16(const float* g, float* l) {
    __builtin_amdgcn_global_load_lds((const __attribute__((address_space(1))) void*)g,
                                     (__attribute__((address_space(3))) void*)l, 16, 0, 0);
}

// --- K0: query rows = norm(node[ent]) + norm(rel[rel]);  32 blocks ---------
__global__ __launch_bounds__(256) void k_prep(const float* __restrict__ node,
                                              const float* __restrict__ rel,
                                              const int* __restrict__ eidx,
                                              const int* __restrict__ ridx,
                                              float* __restrict__ query) {
    int wav  = threadIdx.x >> 6;
    int lane = threadIdx.x & 63;
    int l = blockIdx.x * 4 + wav;                    // 0..127
    int ei = eidx[l], ri = ridx[l];
    float2 e = *reinterpret_cast<const float2*>(node + ei * H + lane * 2);
    float inve = 1.0f / fmaxf(sqrtf(waveReduceSum(e.x * e.x + e.y * e.y)), 1e-12f);
    float2 r = *reinterpret_cast<const float2*>(rel + ri * H + lane * 2);
    float invr = 1.0f / fmaxf(sqrtf(waveReduceSum(r.x * r.x + r.y * r.y)), 1e-12f);
    float2 q;
    q.x = e.x * inve + r.x * invr;
    q.y = e.y * inve + r.y * invr;
    *reinterpret_cast<float2*>(query + l * H + lane * 2) = q;
}

// --- K1: 128x10 exp(L1-dist) tile + psum -----------------------------------
// q read from GLOBAL (64 KB, L2-hot, h-sequential -> L1 line reuse).
// LDS = es tile only (5 KB) -> occupancy wave-capped (~4 blocks/CU).
// Thread: row = tid>>1 (128 rows), cols = (tid&1)*5 .. +5.
// e-scaling folded into fma: d = fma(-e_raw, inv_n, q)  (r13-validated).
// es reads: 2 distinct addrs/instr, delta = 5*128 floats == 0 mod 32 banks
// -> 2-way same-bank, free (m136). No swizzle anywhere.
__global__ __launch_bounds__(256) void k_main(const float* __restrict__ node,
                                              const float* __restrict__ query,
                                              float* __restrict__ out,
                                              float* __restrict__ psum) {
    __shared__ float es[TN * H];    // 5 KB
    __shared__ float invs[TN];

    const int tid  = threadIdx.x;
    const int w    = tid >> 6;
    const int lane = tid & 63;
    const int nb   = blockIdx.x * TN;   // exact, no bounds checks

    // ---- stage es (10 rows = 5 KB) via linear gload16, 2 rows/instr ----
    {
        const int c = lane << 2;        // float offset, 16B per lane
        if (w == 0) {
            gload16(node + (size_t)(nb + 0) * H + c, &es[0 * H]);
            gload16(node + (size_t)(nb + 8) * H + c, &es[8 * H]);
        } else if (w == 1) {
            gload16(node + (size_t)(nb + 2) * H + c, &es[2 * H]);
        } else if (w == 2) {
            gload16(node + (size_t)(nb + 4) * H + c, &es[4 * H]);
        } else {
            gload16(node + (size_t)(nb + 6) * H + c, &es[6 * H]);
        }
    }
    __syncthreads();   // drains DMA

    // ---- inverse norms of the 10 es rows ----
    if (tid < 8 * TN) {
        int row = tid >> 3, seg = tid & 7;
        const float4* p = reinterpret_cast<const float4*>(es + row * H + seg * 16);
        float ss = 0.f;
        #pragma unroll
        for (int u2 = 0; u2 < 4; ++u2) {
            float4 v = p[u2];
            ss += v.x * v.x + v.y * v.y + v.z * v.z + v.w * v.w;
        }
        #pragma unroll
        for (int m = 1; m < 8; m <<= 1) ss += __shfl_xor(ss, m, 64);
        if (seg == 0) invs[row] = 1.0f / fmaxf(sqrtf(ss), 1e-12f);
    }
    __syncthreads();

    // ---- main loop: q from global, e from LDS, fma-folded scaling ----
    const int row = tid >> 1;           // 0..127
    const int cg  = tid & 1;            // col-group: cols cg*5 .. cg*5+4
    const float* qrow = query + (size_t)row * H;
    const int e0 = cg * 5 * H;

    float sj[5];
    #pragma unroll
    for (int j = 0; j < 5; ++j) sj[j] = invs[cg * 5 + j];

    float acc[5] = {};

    #pragma unroll 2
    for (int hc = 0; hc < 32; ++hc) {
        const int h = hc << 2;
        float4 q4 = *reinterpret_cast<const float4*>(qrow + h);
        #pragma unroll
        for (int j = 0; j < 5; ++j) {
            float4 e4 = *reinterpret_cast<const float4*>(&es[e0 + j * H + h]);
            float s = sj[j];
            acc[j] += fabsf(fmaf(-e4.x, s, q4.x)) + fabsf(fmaf(-e4.y, s, q4.y))
                    + fabsf(fmaf(-e4.z, s, q4.z)) + fabsf(fmaf(-e4.w, s, q4.w));
        }
    }

    // ---- epilogue: exp (no max: dist<=~34, f32-safe), store, psum ----
    {
        float p[5];
        float rs = 0.f;
        #pragma unroll
        for (int j = 0; j < 5; ++j) {
            p[j] = __expf(acc[j]);
            rs += p[j];
        }
        float* po = out + (size_t)row * N_NODES + nb + cg * 5;
        #pragma unroll
        for (int j = 0; j < 5; ++j) po[j] = p[j];
        rs += __shfl_xor(rs, 1, 64);    // pair (2r, 2r+1): both col-groups
        if (cg == 0) psum[row * PSTR + blockIdx.x] = rs;
    }
}

// --- K2: finish softmax: per-row sum of 1000 partials, scale ---------------
__global__ __launch_bounds__(256) void k_finish(float* __restrict__ out,
                                                const float* __restrict__ psum) {
    __shared__ float red[4];
    int l = blockIdx.y;
    int tid = threadIdx.x;
    const float* ps = psum + l * PSTR;
    float s = ps[tid] + ps[tid + 256] + ps[tid + 512]
            + (tid < NBLK - 768 ? ps[tid + 768] : 0.f);
    #pragma unroll
    for (int m = 1; m < 64; m <<= 1) s += __shfl_xor(s, m, 64);
    if ((tid & 63) == 0) red[tid >> 6] = s;
    __syncthreads();
    float inv = 1.0f / (red[0] + red[1] + red[2] + red[3]);

    int n4 = blockIdx.x * 256 + tid;           // float4 idx within row (<2500)
    if (n4 < 2500) {
        float4* o = reinterpret_cast<float4*>(out) + (size_t)l * 2500 + n4;
        float4 v = *o;
        v.x *= inv; v.y *= inv; v.z *= inv; v.w *= inv;
        *o = v;
    }
}

extern "C" void kernel_launch(void* const* d_in, const int* in_sizes, int n_in,
                              void* d_out, int out_size, void* d_ws, size_t ws_size,
                              hipStream_t stream) {
    const float* node = (const float*)d_in[0];
    const float* rel  = (const float*)d_in[1];
    const int*   eidx = (const int*)d_in[2];
    const int*   ridx = (const int*)d_in[3];
    float* out = (float*)d_out;

    float* query = (float*)d_ws;              // 16384 floats (64 KB)
    float* psum  = (float*)d_ws + 16384;      // 128*1024 floats (512 KB)

    k_prep<<<32, 256, 0, stream>>>(node, rel, eidx, ridx, query);
    k_main<<<NBLK, 256, 0, stream>>>(node, query, out, psum);

    dim3 gridC((2500 + 255) / 256, L);        // 10 x 128
    k_finish<<<gridC, 256, 0, stream>>>(out, psum);
}

// Round 19
// 25.750 us; speedup vs baseline: 3.8841x; 1.2364x over previous
//
#include <hip/hip_runtime.h>
#include <math.h>

#define N_NODES 10000
#define N_REL   500
#define H       128
#define L       128

#define TN    20     // n-tile: 500 * 20 = 10000 exactly
#define NBLK  500    // grid of k_main (2 blocks/CU)
#define PSTR  512    // psum row stride

__device__ __forceinline__ void gload16(const float* g, float* l) {
    __builtin_amdgcn_global_load_lds((const __attribute__((address_space(1))) void*)g,
                                     (__attribute__((address_space(3))) void*)l, 16, 0, 0);
}

// --- K1: per-block query rebuild + 128x20 exp(L1-dist) tile + psum ---------
// r7 structure (best clean: 27.0 us) minus the A4 scale pass: the es rows
// stay RAW in LDS and the inverse norm is folded into the inner-loop FMA
// (|q - e*s| = |fma(-e,s,q)|, same 2 VALU/element; validated r13/r18).
// LDS content swizzle: stored[row][c] = src[row][c ^ ((row&7)<<2)]
// Waves split h 4x32; lane tile 8l x 5n: l = grp+16i, n = nl+4j.
__global__ __launch_bounds__(256, 2) void k_main(const float* __restrict__ node,
                                                 const float* __restrict__ rel,
                                                 const int* __restrict__ eidx,
                                                 const int* __restrict__ ridx,
                                                 float* __restrict__ out,
                                                 float* __restrict__ psum) {
    __shared__ union {
        float qs[L * H];            // 64 KB  (build + main-loop phase)
        float red[4][128][21];      // 43 KB  (merge phase, aliases qs)
    } u;
    __shared__ float es[TN * H];    // 10 KB
    __shared__ float invs[TN];

    const int tid  = threadIdx.x;
    const int w    = tid >> 6;          // wave id = h-segment in main loop
    const int lane = tid & 63;
    const int grp  = lane >> 2;         // 0..15
    const int nl   = lane & 3;          // 0..3
    const int nb   = blockIdx.x * TN;   // exact, no bounds checks

    // ---- A1: issue es staging DMA (overlaps the query build below) ----
    {
        const int c0   = (lane & 31) << 2;
        const int roff = lane >> 5;
        #pragma unroll
        for (int k = 0; k < 10; ++k) {
            if ((k & 3) == w) {
                int r = k * 2;
                int row = r + roff;
                int g = (row & 7) << 2;
                gload16(node + (size_t)(nb + row) * H + (c0 ^ g), &es[r * H]);
            }
        }
    }

    // ---- A2: build all 128 query rows into qs (redundant per block; ----
    // ---- gathers are L2-hot: only 128KB unique data shared by all)  ----
    #pragma unroll
    for (int it = 0; it < 4; ++it) {
        int row = it * 32 + (tid >> 3);
        int seg = tid & 7;
        int ei = eidx[row], ri = ridx[row];
        const float4* pe = reinterpret_cast<const float4*>(node + (size_t)ei * H + seg * 16);
        const float4* pr = reinterpret_cast<const float4*>(rel  + (size_t)ri * H + seg * 16);
        float4 ev[4], rv[4];
        #pragma unroll
        for (int u2 = 0; u2 < 4; ++u2) { ev[u2] = pe[u2]; rv[u2] = pr[u2]; }
        float se = 0.f, sr = 0.f;
        #pragma unroll
        for (int u2 = 0; u2 < 4; ++u2) {
            se += ev[u2].x * ev[u2].x + ev[u2].y * ev[u2].y
                + ev[u2].z * ev[u2].z + ev[u2].w * ev[u2].w;
            sr += rv[u2].x * rv[u2].x + rv[u2].y * rv[u2].y
                + rv[u2].z * rv[u2].z + rv[u2].w * rv[u2].w;
        }
        se += __shfl_xor(se, 1, 64); se += __shfl_xor(se, 2, 64); se += __shfl_xor(se, 4, 64);
        sr += __shfl_xor(sr, 1, 64); sr += __shfl_xor(sr, 2, 64); sr += __shfl_xor(sr, 4, 64);
        float inve = 1.0f / fmaxf(sqrtf(se), 1e-12f);
        float invr = 1.0f / fmaxf(sqrtf(sr), 1e-12f);
        int g = (row & 7) << 2;
        float* dst = u.qs + row * H;
        #pragma unroll
        for (int u2 = 0; u2 < 4; ++u2) {
            float4 q;
            q.x = ev[u2].x * inve + rv[u2].x * invr;
            q.y = ev[u2].y * inve + rv[u2].y * invr;
            q.z = ev[u2].z * inve + rv[u2].z * invr;
            q.w = ev[u2].w * inve + rv[u2].w * invr;
            int c = (seg * 16 + u2 * 4) ^ g;        // 16B-aligned, swizzled
            *reinterpret_cast<float4*>(dst + c) = q;
        }
    }
    __syncthreads();   // drains es DMA (vmcnt) + qs LDS writes

    // ---- A3: inverse norms of the 20 es rows (swizzle-invariant) ----
    if (tid < 8 * TN) {
        int row = tid >> 3, seg = tid & 7;
        const float4* p = reinterpret_cast<const float4*>(es + row * H + seg * 16);
        float ss = 0.f;
        #pragma unroll
        for (int u2 = 0; u2 < 4; ++u2) {
            float4 v = p[u2];
            ss += v.x * v.x + v.y * v.y + v.z * v.z + v.w * v.w;
        }
        #pragma unroll
        for (int m = 1; m < 8; m <<= 1) ss += __shfl_xor(ss, m, 64);
        if (seg == 0) invs[row] = 1.0f / fmaxf(sqrtf(ss), 1e-12f);
    }
    __syncthreads();

    // ---- B: main loop, 8 h-quads; e raw from LDS, scale fused in fma ----
    const int hs = w * 32;
    const int gq = (grp & 7) << 2;
    int gej[5];
    float sj[5];
    #pragma unroll
    for (int j = 0; j < 5; ++j) {
        gej[j] = ((nl + 4 * j) & 7) << 2;
        sj[j]  = invs[nl + 4 * j];
    }

    float acc[8][5] = {};

    #pragma unroll
    for (int hc = 0; hc < 8; ++hc) {
        const int h = hs + (hc << 2);
        float4 qf[8], ef[5];
        #pragma unroll
        for (int i = 0; i < 8; ++i)
            qf[i] = *reinterpret_cast<const float4*>(&u.qs[(grp + 16 * i) * H + (h ^ gq)]);
        #pragma unroll
        for (int j = 0; j < 5; ++j)
            ef[j] = *reinterpret_cast<const float4*>(&es[(nl + 4 * j) * H + (h ^ gej[j])]);
        #pragma unroll
        for (int i = 0; i < 8; ++i)
            #pragma unroll
            for (int j = 0; j < 5; ++j) {
                float s = sj[j];
                acc[i][j] += fabsf(fmaf(-ef[j].x, s, qf[i].x))
                           + fabsf(fmaf(-ef[j].y, s, qf[i].y))
                           + fabsf(fmaf(-ef[j].z, s, qf[i].z))
                           + fabsf(fmaf(-ef[j].w, s, qf[i].w));
            }
    }

    // ---- merge 4 h-segment partials through LDS (aliases qs) ----
    __syncthreads();
    #pragma unroll
    for (int i = 0; i < 8; ++i)
        #pragma unroll
        for (int j = 0; j < 5; ++j)
            u.red[w][grp + 16 * i][nl + 4 * j] = acc[i][j];
    __syncthreads();

    // ---- epilogue: exp (no max: dist<=~34, f32-safe), store, psum ----
    {
        const int l  = tid >> 1;
        const int n0 = (tid & 1) * 10;
        float p[10];
        float rs = 0.f;
        #pragma unroll
        for (int k = 0; k < 10; ++k) {
            float d = u.red[0][l][n0 + k] + u.red[1][l][n0 + k]
                    + u.red[2][l][n0 + k] + u.red[3][l][n0 + k];
            p[k] = __expf(d);
            rs += p[k];
        }
        float* po = out + (size_t)l * N_NODES + nb + n0;
        #pragma unroll
        for (int k = 0; k < 5; ++k)
            *reinterpret_cast<float2*>(po + 2 * k) = make_float2(p[2 * k], p[2 * k + 1]);
        rs += __shfl_xor(rs, 1, 64);
        if ((tid & 1) == 0) psum[l * PSTR + blockIdx.x] = rs;
    }
}

// --- K2: finish softmax: per-row sum of 500 partials, scale ----------------
__global__ __launch_bounds__(256) void k_finish(float* __restrict__ out,
                                                const float* __restrict__ psum) {
    __shared__ float red[4];
    int l = blockIdx.y;
    int tid = threadIdx.x;
    const float* ps = psum + l * PSTR;
    float s = ps[tid] + (tid < NBLK - 256 ? ps[tid + 256] : 0.f);
    #pragma unroll
    for (int m = 1; m < 64; m <<= 1) s += __shfl_xor(s, m, 64);
    if ((tid & 63) == 0) red[tid >> 6] = s;
    __syncthreads();
    float inv = 1.0f / (red[0] + red[1] + red[2] + red[3]);

    int n4 = blockIdx.x * 256 + tid;           // float4 idx within row (<2500)
    if (n4 < 2500) {
        float4* o = reinterpret_cast<float4*>(out) + (size_t)l * 2500 + n4;
        float4 v = *o;
        v.x *= inv; v.y *= inv; v.z *= inv; v.w *= inv;
        *o = v;
    }
}

extern "C" void kernel_launch(void* const* d_in, const int* in_sizes, int n_in,
                              void* d_out, int out_size, void* d_ws, size_t ws_size,
                              hipStream_t stream) {
    const float* node = (const float*)d_in[0];
    const float* rel  = (const float*)d_in[1];
    const int*   eidx = (const int*)d_in[2];
    const int*   ridx = (const int*)d_in[3];
    float* out = (float*)d_out;

    float* psum = (float*)d_ws;               // 128*512 floats = 256 KB

    k_main<<<NBLK, 256, 0, stream>>>(node, rel, eidx, ridx, out, psum);

    dim3 gridC((2500 + 255) / 256, L);        // 10 x 128
    k_finish<<<gridC, 256, 0, stream>>>(out, psum);
}